// Round 5
// baseline (26.721 us; speedup 1.0000x reference)
//
#include <hip/hip_runtime.h>
#include <hip/hip_bf16.h>

#define SEP_ID 102
#define BB 64
#define SS 512
#define HH 1024

// Sum rows [lo, end) (consecutive) of the float4 column at rb into a0/a1.
__device__ __forceinline__ void accum_rows(const float* __restrict__ rb,
                                           int lo, int end,
                                           float4& a0, float4& a1)
{
    int s = lo;
    for (; s + 3 < end; s += 4) {        // 4 independent 16B loads in flight
        float4 v0 = *reinterpret_cast<const float4*>(rb + (size_t)(s    ) * HH);
        float4 v1 = *reinterpret_cast<const float4*>(rb + (size_t)(s + 1) * HH);
        float4 v2 = *reinterpret_cast<const float4*>(rb + (size_t)(s + 2) * HH);
        float4 v3 = *reinterpret_cast<const float4*>(rb + (size_t)(s + 3) * HH);
        a0.x += v0.x + v2.x;  a0.y += v0.y + v2.y;
        a0.z += v0.z + v2.z;  a0.w += v0.w + v2.w;
        a1.x += v1.x + v3.x;  a1.y += v1.y + v3.y;
        a1.z += v1.z + v3.z;  a1.w += v1.w + v3.w;
    }
    for (; s < end; ++s) {
        float4 v = *reinterpret_cast<const float4*>(rb + (size_t)s * HH);
        a0.x += v.x; a0.y += v.y; a0.z += v.z; a0.w += v.w;
    }
}

// Shared meta scan: first/last/count of SEP in batch b's id row.
__device__ __forceinline__ void meta_scan(const int* __restrict__ ids, int b,
                                          int t, int nthr,
                                          int& first, int& lead_end, int& has)
{
    __shared__ int s_first, s_last, s_cnt;
    if (t == 0) { s_first = SS; s_last = -1; s_cnt = 0; }
    __syncthreads();
    for (int k = t; k < SS; k += nthr) {
        if (ids[b * SS + k] == SEP_ID) {
            atomicMin(&s_first, k);
            atomicMax(&s_last, k);
            atomicAdd(&s_cnt, 1);
        }
    }
    __syncthreads();
    int cnt  = s_cnt;
    has      = (cnt >= 1) ? 1 : 0;
    first    = has ? s_first : 0;
    lead_end = (cnt >= 2) ? s_last : SS;
}

// Balanced pool: 1-D grid of NS*64 blocks, 256 threads (4 waves) each.
// Swizzle: q=id>>6 (s-chunk), r=id&63, b=(r+q)&63 -> each CU's co-resident
// blocks hit different batches at stratified chunk positions.
// Block covers ALL of H (256 thr x float4); rows = chunk ∩ segment ranges.
// part layout: part[(id*2 + seg)*HH + h], seg 0=title 1=lead.
__global__ __launch_bounds__(256) void pool_kernel(
    const float* __restrict__ hs,
    const int*   __restrict__ ids,
    float*       __restrict__ part,
    int NS, int SC)
{
    const int id = blockIdx.x;
    const int q  = id >> 6;            // s-chunk index
    const int b  = ((id & 63) + q) & 63;
    const int t  = threadIdx.x;

    int first, lead_end, has;
    meta_scan(ids, b, t, 256, first, lead_end, has);

    const int s0 = q * SC;
    const int s1 = (s0 + SC < SS) ? s0 + SC : SS;

    // disjoint ranges clipped to this chunk
    int tlo = (s0 > 1) ? s0 : 1;
    int thi = has ? ((first < s1) ? first : s1) : 0;
    int llo = (s0 > first + 1) ? s0 : first + 1;
    int lhi = has ? ((lead_end < s1) ? lead_end : s1) : 0;

    const float* rb = hs + (size_t)b * SS * HH + t * 4;
    float4 aT0 = make_float4(0.f,0.f,0.f,0.f), aT1 = make_float4(0.f,0.f,0.f,0.f);
    float4 aL0 = make_float4(0.f,0.f,0.f,0.f), aL1 = make_float4(0.f,0.f,0.f,0.f);
    accum_rows(rb, tlo, thi, aT0, aT1);
    accum_rows(rb, llo, lhi, aL0, aL1);

    size_t base = ((size_t)id * 2) * HH + t * 4;
    float4 oT = make_float4(aT0.x+aT1.x, aT0.y+aT1.y, aT0.z+aT1.z, aT0.w+aT1.w);
    float4 oL = make_float4(aL0.x+aL1.x, aL0.y+aL1.y, aL0.z+aL1.z, aL0.w+aL1.w);
    *reinterpret_cast<float4*>(part + base)      = oT;
    *reinterpret_cast<float4*>(part + base + HH) = oL;
}

// Finalize: one block per batch, 256 threads; fixed-order sum over NS chunk
// partials per segment (deterministic), divide by analytic counts, store.
__global__ __launch_bounds__(256) void finalize_kernel(
    const float* __restrict__ part,
    const int*   __restrict__ ids,
    float*       __restrict__ out,
    int NS)
{
    const int b = blockIdx.x;
    const int t = threadIdx.x;

    int first, lead_end, has;
    meta_scan(ids, b, t, 256, first, lead_end, has);

    float4 sT = make_float4(0.f,0.f,0.f,0.f);
    float4 sL = make_float4(0.f,0.f,0.f,0.f);
    #pragma unroll 4
    for (int q = 0; q < NS; ++q) {
        int id = q * 64 + ((b - q) & 63);          // inverse of pool swizzle
        size_t p = ((size_t)id * 2) * HH + t * 4;
        float4 a = *reinterpret_cast<const float4*>(part + p);
        float4 c = *reinterpret_cast<const float4*>(part + p + HH);
        sT.x += a.x; sT.y += a.y; sT.z += a.z; sT.w += a.w;
        sL.x += c.x; sL.y += c.y; sL.z += c.z; sL.w += c.w;
    }

    int cT = has ? (first - 1) : 0;            if (cT < 0) cT = 0;
    int cL = has ? (lead_end - first - 1) : 0; if (cL < 0) cL = 0;

    float4 oT, oL;
    if (cT > 0) { float d = (float)cT; oT = make_float4(sT.x/d, sT.y/d, sT.z/d, sT.w/d); }
    else        { oT = make_float4(0.f,0.f,0.f,0.f); }
    if (cL > 0) { float d = (float)cL; oL = make_float4(sL.x/d, sL.y/d, sL.z/d, sL.w/d); }
    else        { oL = make_float4(0.f,0.f,0.f,0.f); }

    *reinterpret_cast<float4*>(out + (size_t)b * HH + t * 4)                   = oT;
    *reinterpret_cast<float4*>(out + (size_t)BB * HH + (size_t)b * HH + t * 4) = oL;
}

extern "C" void kernel_launch(void* const* d_in, const int* in_sizes, int n_in,
                              void* d_out, int out_size, void* d_ws, size_t ws_size,
                              hipStream_t stream) {
    const float* hs = (const float*)d_in[0];
    const int*  ids = (const int*)d_in[1];
    float* out = (float*)d_out;

    // partials: NS*64 blocks * 2 segs * HH floats
    int NS = 16;
    while (NS > 1 && (size_t)NS * 64 * 2 * HH * sizeof(float) > ws_size) NS >>= 1;
    float* part = (float*)d_ws;

    int SC = (SS + NS - 1) / NS;
    pool_kernel<<<NS * 64, 256, 0, stream>>>(hs, ids, part, NS, SC);
    finalize_kernel<<<BB, 256, 0, stream>>>(part, ids, out, NS);
}

// Round 6
// 21.440 us; speedup vs baseline: 1.2463x; 1.2463x over previous
//
#include <hip/hip_runtime.h>
#include <hip/hip_bf16.h>

#define SEP_ID 102
#define BB 64
#define SS 512
#define HH 1024

// Accumulate rows {s = lo+wv, lo+wv+16, ...} < end (wave-strided) of the
// 256-float slice at rb into a0/a1 (two accumulators to break dep chains).
// Rows in this range belong to exactly one segment -> no weight FMAs.
__device__ __forceinline__ void accum_range(const float* __restrict__ rb,
                                            int lo, int end, int wv,
                                            float4& a0, float4& a1)
{
    int s = lo + wv;
    for (; s + 48 < end; s += 64) {          // 4 independent 16B loads in flight
        float4 v0 = *reinterpret_cast<const float4*>(rb + (size_t)(s     ) * HH);
        float4 v1 = *reinterpret_cast<const float4*>(rb + (size_t)(s + 16) * HH);
        float4 v2 = *reinterpret_cast<const float4*>(rb + (size_t)(s + 32) * HH);
        float4 v3 = *reinterpret_cast<const float4*>(rb + (size_t)(s + 48) * HH);
        a0.x += v0.x + v2.x;  a0.y += v0.y + v2.y;
        a0.z += v0.z + v2.z;  a0.w += v0.w + v2.w;
        a1.x += v1.x + v3.x;  a1.y += v1.y + v3.y;
        a1.z += v1.z + v3.z;  a1.w += v1.w + v3.w;
    }
    for (; s < end; s += 16) {
        float4 v = *reinterpret_cast<const float4*>(rb + (size_t)s * HH);
        a0.x += v.x; a0.y += v.y; a0.z += v.z; a0.w += v.w;
    }
}

// grid = (H/256 = 4, B = 64); block = 1024 threads = 16 waves.
// Block (hq, b) owns a 256-float slice of H for batch b. Wave wv handles
// rows interleaved at stride 16 within each segment's disjoint range.
__global__ __launch_bounds__(1024) void seg_pool_kernel(
    const float* __restrict__ hs,
    const int*   __restrict__ ids,
    float*       __restrict__ out)
{
    const int hq   = blockIdx.x;       // 0..3
    const int b    = blockIdx.y;       // 0..63
    const int tid  = threadIdx.x;
    const int lane = tid & 63;
    const int wv   = tid >> 6;         // 0..15

    // ---- meta scan (block-shared atomics; ids row is 2 KB, L2-hot) ----
    __shared__ int s_first, s_last, s_cnt;
    if (tid == 0) { s_first = SS; s_last = -1; s_cnt = 0; }
    __syncthreads();
    if (tid < SS) {
        if (ids[b * SS + tid] == SEP_ID) {
            atomicMin(&s_first, tid);
            atomicMax(&s_last, tid);
            atomicAdd(&s_cnt, 1);
        }
    }
    __syncthreads();
    const int cnt      = s_cnt;
    const int has      = (cnt >= 1) ? 1 : 0;
    const int first    = has ? s_first : 0;
    const int lead_end = (cnt >= 2) ? s_last : SS;

    const float* rb = hs + (size_t)b * SS * HH + hq * 256 + lane * 4;

    // ---- disjoint segment ranges: title [1, first), lead (first, lead_end) ----
    float4 aT0 = make_float4(0.f,0.f,0.f,0.f), aT1 = make_float4(0.f,0.f,0.f,0.f);
    float4 aL0 = make_float4(0.f,0.f,0.f,0.f), aL1 = make_float4(0.f,0.f,0.f,0.f);

    const int tEnd = has ? first    : 0;
    const int lEnd = has ? lead_end : 0;
    accum_range(rb, 1,         tEnd, wv, aT0, aT1);
    accum_range(rb, first + 1, lEnd, wv, aL0, aL1);

    float4 aT = make_float4(aT0.x + aT1.x, aT0.y + aT1.y, aT0.z + aT1.z, aT0.w + aT1.w);
    float4 aL = make_float4(aL0.x + aL1.x, aL0.y + aL1.y, aL0.z + aL1.z, aL0.w + aL1.w);

    // ---- cross-wave reduce via LDS (32 KB) ----
    __shared__ float4 ldsT[16][64];
    __shared__ float4 ldsL[16][64];
    ldsT[wv][lane] = aT;
    ldsL[wv][lane] = aL;
    __syncthreads();

    if (wv == 0) {
        float4 sT = make_float4(0.f,0.f,0.f,0.f);
        #pragma unroll
        for (int j = 0; j < 16; ++j) {              // fixed order: deterministic
            float4 a = ldsT[j][lane];
            sT.x += a.x; sT.y += a.y; sT.z += a.z; sT.w += a.w;
        }
        int cT = has ? (first - 1) : 0; if (cT < 0) cT = 0;
        float4 o;
        if (cT > 0) { float d = (float)cT; o = make_float4(sT.x/d, sT.y/d, sT.z/d, sT.w/d); }
        else        { o = make_float4(0.f,0.f,0.f,0.f); }
        *reinterpret_cast<float4*>(out + (size_t)b * HH + hq * 256 + lane * 4) = o;
    } else if (wv == 1) {
        float4 sL = make_float4(0.f,0.f,0.f,0.f);
        #pragma unroll
        for (int j = 0; j < 16; ++j) {
            float4 a = ldsL[j][lane];
            sL.x += a.x; sL.y += a.y; sL.z += a.z; sL.w += a.w;
        }
        int cL = has ? (lead_end - first - 1) : 0; if (cL < 0) cL = 0;
        float4 o;
        if (cL > 0) { float d = (float)cL; o = make_float4(sL.x/d, sL.y/d, sL.z/d, sL.w/d); }
        else        { o = make_float4(0.f,0.f,0.f,0.f); }
        *reinterpret_cast<float4*>(out + (size_t)BB * HH + (size_t)b * HH + hq * 256 + lane * 4) = o;
    }
}

extern "C" void kernel_launch(void* const* d_in, const int* in_sizes, int n_in,
                              void* d_out, int out_size, void* d_ws, size_t ws_size,
                              hipStream_t stream) {
    const float* hs = (const float*)d_in[0];
    const int*  ids = (const int*)d_in[1];
    float* out = (float*)d_out;

    dim3 grid(HH / 256, BB);
    seg_pool_kernel<<<grid, 1024, 0, stream>>>(hs, ids, out);
}